// Round 16
// baseline (3173.650 us; speedup 1.0000x reference)
//
#include <hip/hip_runtime.h>
#include <hip/hip_bf16.h>

#define B_   64
#define S_   128
#define T_   64
#define H_   1024
#define E_   512
#define V_   16000
#define ENC_ 2048
#define XDIM_ (E_ + ENC_)   // 2560
#define G3_  (3 * H_)       // 3072
#define QGH_ (4 * H_)       // 4096 (bhq layout: ba | bhh_r | bhh_z | bhh_n)
#define NB_  256            // persistent grid size

// dynamic LDS layout (bytes)
#define SMEM_ENCP   0        // 32 rows x 2048 B = 65536
#define SMEM_SCR    65536    // phase scratch (max: C redp 32768 + gt 4096)
#define SMEM_TOTAL  102400

typedef __attribute__((ext_vector_type(8))) short bf16x8;
typedef __attribute__((ext_vector_type(8))) unsigned short u16x8;
typedef __attribute__((ext_vector_type(4))) float f32x4;

__device__ __forceinline__ ushort f2bf(float x) {
    __hip_bfloat16 h = __float2bfloat16(x);
    return *reinterpret_cast<ushort*>(&h);
}
__device__ __forceinline__ float bf2f(ushort u) {
    return __uint_as_float((unsigned)u << 16);
}
__device__ __forceinline__ float sigmoidf_(float x) {
    return 1.f / (1.f + expf(-x));
}

// Relaxed agent-scope atomic store (R12-proven publication model):
// lands at the LLC coherence point; ordering to the flag store is provided
// by __syncthreads() draining each wave's vmcnt before the flag is stored.
template <typename T>
__device__ __forceinline__ void atstore(T* p, T v) {
    __hip_atomic_store(p, v, __ATOMIC_RELAXED, __HIP_MEMORY_SCOPE_AGENT);
}

// async global->LDS, 16B per lane
__device__ __forceinline__ void gload_lds16(const ushort* g, ushort* l) {
    __builtin_amdgcn_global_load_lds(
        (const __attribute__((address_space(1))) unsigned int*)g,
        (__attribute__((address_space(3))) unsigned int*)l, 16, 0, 0);
}

__device__ __forceinline__ void pollge(const unsigned* f, unsigned v) {
    while (__hip_atomic_load(f, __ATOMIC_RELAXED, __HIP_MEMORY_SCOPE_AGENT) < v)
        __builtin_amdgcn_s_sleep(1);
}
__device__ __forceinline__ void sigrel(unsigned* f, unsigned v) {
    __hip_atomic_store(f, v, __ATOMIC_RELAXED, __HIP_MEMORY_SCOPE_AGENT);
}

// ---------------------------------------------------------------------------
// m97-structure GEMM: C[M,N] = A[M,K] @ W[N,K]^T + bias[N]
// ---------------------------------------------------------------------------
__global__ __launch_bounds__(256) void gemm128_bf16(
    const ushort* __restrict__ A, int lda,
    const ushort* __restrict__ W, int ldw,
    const float* __restrict__ bias,
    float* __restrict__ Cf, ushort* __restrict__ Cb, int ldc,
    int K)
{
    const int bn0 = blockIdx.x * 128;
    const int bm0 = blockIdx.y * 128;
    const int tid = threadIdx.x;
    const int wv  = tid >> 6;
    const int lane = tid & 63;

    __shared__ ushort As[128 * 32];
    __shared__ ushort Bs[128 * 32];

    const int srow = tid >> 2;
    const int scol = (tid & 3) * 8;

    const ushort* gA0 = A + (size_t)(bm0 + srow) * lda + scol;
    const ushort* gA1 = gA0 + (size_t)64 * lda;
    const ushort* gB0 = W + (size_t)(bn0 + srow) * ldw + scol;
    const ushort* gB1 = gB0 + (size_t)64 * ldw;

    ushort* lA0 = &As[tid * 8];
    ushort* lA1 = &As[2048 + tid * 8];
    ushort* lB0 = &Bs[tid * 8];
    ushort* lB1 = &Bs[2048 + tid * 8];

    const int wr0 = (wv >> 1) * 64;
    const int wc0 = (wv & 1) * 64;
    const int frow = lane & 15;
    const int fk   = (lane >> 4) * 8;

    f32x4 acc[4][4];
#pragma unroll
    for (int i = 0; i < 4; ++i)
#pragma unroll
        for (int j = 0; j < 4; ++j) acc[i][j] = (f32x4){0.f, 0.f, 0.f, 0.f};

    for (int k0 = 0; k0 < K; k0 += 32) {
        gload_lds16(gA0 + k0, lA0);
        gload_lds16(gA1 + k0, lA1);
        gload_lds16(gB0 + k0, lB0);
        gload_lds16(gB1 + k0, lB1);
        __syncthreads();

        bf16x8 af[4], bf[4];
#pragma unroll
        for (int rb = 0; rb < 4; ++rb)
            af[rb] = *reinterpret_cast<const bf16x8*>(&As[(wr0 + rb * 16 + frow) * 32 + fk]);
#pragma unroll
        for (int cb = 0; cb < 4; ++cb)
            bf[cb] = *reinterpret_cast<const bf16x8*>(&Bs[(wc0 + cb * 16 + frow) * 32 + fk]);
#pragma unroll
        for (int rb = 0; rb < 4; ++rb)
#pragma unroll
            for (int cb = 0; cb < 4; ++cb)
                acc[rb][cb] = __builtin_amdgcn_mfma_f32_16x16x32_bf16(af[rb], bf[cb], acc[rb][cb], 0, 0, 0);
        __syncthreads();
    }

    const int quad = lane >> 4;
#pragma unroll
    for (int cb = 0; cb < 4; ++cb) {
        const int col = bn0 + wc0 + cb * 16 + frow;
        const float bv = bias ? bias[col] : 0.f;
#pragma unroll
        for (int rb = 0; rb < 4; ++rb) {
            const int row0 = bm0 + wr0 + rb * 16 + quad * 4;
            f32x4 a = acc[rb][cb];
#pragma unroll
            for (int r = 0; r < 4; ++r) {
                const float val = a[r] + bv;
                if (Cb) Cb[(size_t)(row0 + r) * ldc + col] = f2bf(val);
                else    Cf[(size_t)(row0 + r) * ldc + col] = val;
            }
        }
    }
}

// ---------------------------------------------------------------------------
// ONE merged pack kernel (R15): conversions, bias pack, flag zero, emb gather.
// ---------------------------------------------------------------------------
__global__ __launch_bounds__(256) void pack_all(
    const float* __restrict__ enc,     // (B,S,ENC)
    const float* __restrict__ Wo,      // (V,H)
    const float* __restrict__ Wa,      // (H, 3072)
    const float* __restrict__ W_hh,    // (3H, H)
    const float* __restrict__ W_ih,    // (3H, 2560)
    const float* __restrict__ enc_h,   // (B,H)
    const float* __restrict__ ba,
    const float* __restrict__ b_hh,
    const float* __restrict__ b_ih,    // unused here (giemb GEMM adds it)
    const int*   __restrict__ target,
    const float* __restrict__ emb,
    ushort* __restrict__ enc_bf,
    ushort* __restrict__ Wo_bf,
    ushort* __restrict__ Wae_bf,
    ushort* __restrict__ Whq_bf,
    ushort* __restrict__ Wie_bf,
    ushort* __restrict__ Wiee_bf,
    ushort* __restrict__ ench_bf,
    ushort* __restrict__ Xemb_bf,
    float*  __restrict__ bhq,
    unsigned* __restrict__ flags)
{
    const size_t stride = (size_t)gridDim.x * 256;
    const size_t i0 = (size_t)blockIdx.x * 256 + threadIdx.x;

    switch (blockIdx.y) {
    case 0:
        for (size_t i = i0; i < (size_t)B_ * S_ * ENC_; i += stride)
            enc_bf[i] = f2bf(enc[i]);
        break;
    case 1:
        for (size_t i = i0; i < (size_t)V_ * H_; i += stride)
            Wo_bf[i] = f2bf(Wo[i]);
        break;
    case 2:
        for (size_t i = i0; i < (size_t)H_ * ENC_; i += stride) {
            const size_t r = i >> 11, c = i & 2047;
            Wae_bf[i] = f2bf(Wa[r * 3072 + 1024 + c]);
        }
        break;
    case 3:
        for (size_t i = i0; i < (size_t)H_ * H_; i += stride) {
            const size_t r = i >> 10, c = i & 1023;
            Whq_bf[i] = f2bf(Wa[r * 3072 + c]);
        }
        break;
    case 4:
        for (size_t i = i0; i < (size_t)G3_ * H_; i += stride)
            Whq_bf[(size_t)H_ * H_ + i] = f2bf(W_hh[i]);
        break;
    case 5:
        for (size_t i = i0; i < (size_t)G3_ * ENC_; i += stride) {
            const size_t r = i >> 11, c = i & 2047;
            Wie_bf[i] = f2bf(W_ih[r * 2560 + 512 + c]);
        }
        break;
    case 6:
        for (size_t i = i0; i < (size_t)G3_ * E_; i += stride) {
            const size_t r = i >> 9, c = i & 511;
            Wiee_bf[i] = f2bf(W_ih[r * 2560 + c]);
        }
        break;
    case 7:
        for (size_t i = i0; i < (size_t)B_ * H_ + 4096 + 32768; i += stride) {
            if (i < (size_t)B_ * H_) {
                ench_bf[i] = f2bf(enc_h[i]);
            } else if (i < (size_t)B_ * H_ + 4096) {
                const int j = (int)(i - (size_t)B_ * H_);
                bhq[j] = (j < H_) ? ba[j] : b_hh[j - H_];
            } else {
                flags[i - (size_t)B_ * H_ - 4096] = 0u;
            }
        }
        break;
    case 8:
        for (size_t i = i0; i < (size_t)B_ * T_ * E_; i += stride) {
            const int row = (int)(i >> 9);
            const int c = (int)(i & 511);
            const int b = row >> 6, t = row & 63;
            const int tok = (t == 0) ? 1 : target[b * T_ + t - 1];
            Xemb_bf[i] = f2bf(emb[(size_t)tok * E_ + c]);
        }
        break;
    }
}

// ---------------------------------------------------------------------------
// Persistent decoder — CLOSED-GROUP dependency pipelines.
// 4 independent groups of 64 blocks; group g = blk>>6 owns b in [g*16,+16)
// end-to-end. Per step (all waits intra-group, blocks [g*64, +64)):
//   [A-wait: hflag g-group] A: q tile (b-rows g*16.., col qc0) -> aflag
//   [B-wait: aflag g-group] B: scores -> sib sflag -> softmax+ctx -> xflag
//   [C-wait: xflag g-group] C: gh+gi fused + GRU (b-rows g*16.., j-slice
//                              jt=blk&63) -> hflag
// Groups never synchronize with each other -> pipelines slide independently.
// All data step-unique; publication relaxed-atomic + syncthreads (R12 model).
// ---------------------------------------------------------------------------
__global__ __launch_bounds__(512) void decoder_persist(
    const ushort* __restrict__ encp,   // (B,S,H) bf16
    const ushort* __restrict__ enc,    // (B,S,ENC) bf16
    const ushort* __restrict__ ench,   // (B,H) bf16 h0
    const float*  __restrict__ ench_f, // (B,H) fp32 h0
    const ushort* __restrict__ Whq,    // (4096,1024) bf16: [Wa_q | Whh_r | Whh_z | Whh_n]
    const ushort* __restrict__ Wie,    // (3072,2048) bf16
    const float*  __restrict__ bhq,    // (4096): [ba | bhh_r | bhh_z | bhh_n]
    const float*  __restrict__ vvec,   // (1024)
    const float*  __restrict__ giemb,  // (B*T,3H) fp32 (incl b_ih)
    float* __restrict__ q_all,         // (T,B,H) step-unique
    float* __restrict__ scores_all,    // (T,B,S) step-unique
    ushort* __restrict__ ctx_all,      // (T,B,ENC) bf16 step-unique
    float* __restrict__ hall_f,        // (B,T,H)
    ushort* __restrict__ hall_b,       // (B,T,H)
    unsigned* __restrict__ aflag,
    unsigned* __restrict__ sflag,
    unsigned* __restrict__ xflag,
    unsigned* __restrict__ hflag)
{
    extern __shared__ __align__(16) char smem[];
    const int blk = blockIdx.x;
    const int tid = threadIdx.x;
    const int wv = tid >> 6;
    const int lane = tid & 63;
    const int frow = lane & 15;
    const int fk = (lane >> 4) * 8;

    const int grp = blk >> 6;          // closed group 0..3 (owns b [grp*16,+16))
    const int g0  = grp * 64;          // first block of the group
    const int ab = blk >> 2;           // B-task: b  (note ab>>4 == grp)
    const int aq = blk & 3;            // B-task: quarter
    const int qbg = grp;               // A-task: b-group == grp
    const int qc0 = (blk & 63) * 16;   // A-task: col base (0..1008)
    const int jt = blk & 63;           // C-task: j-slice (group-local!)
    const int cb0 = grp * 16;          // C-task: b base == group's b's

    // ---- preload encp slice (b=ab, rows aq*32..+32) into LDS ----
    {
        const char* src = (const char*)(encp + ((size_t)ab * S_ + aq * 32) * H_);
#pragma unroll
        for (int r = 0; r < 8; ++r) {
            const int ci = r * 8 + wv;
            gload_lds16((const ushort*)(src + ci * 1024 + lane * 16),
                        (ushort*)(smem + SMEM_ENCP + ci * 1024 + lane * 16));
        }
    }
    float vr[16];
    *reinterpret_cast<f32x4*>(&vr[0])  = *reinterpret_cast<const f32x4*>(vvec + lane * 8);
    *reinterpret_cast<f32x4*>(&vr[4])  = *reinterpret_cast<const f32x4*>(vvec + lane * 8 + 4);
    *reinterpret_cast<f32x4*>(&vr[8])  = *reinterpret_cast<const f32x4*>(vvec + 512 + lane * 8);
    *reinterpret_cast<f32x4*>(&vr[12]) = *reinterpret_cast<const f32x4*>(vvec + 512 + lane * 8 + 4);
    __syncthreads();

    for (int t = 0; t < T_; ++t) {
        const ushort* hb = t ? (hall_b + (size_t)(t - 1) * H_) : ench;
        const float*  hf = t ? (hall_f + (size_t)(t - 1) * H_) : ench_f;
        const int ldh = t ? (T_ * H_) : H_;
        float* q = q_all + (size_t)t * B_ * H_;
        float* scores = scores_all + (size_t)t * B_ * S_;
        ushort* ctx = ctx_all + (size_t)t * B_ * ENC_;

        // -------- A-wait: h(t-1) rows [grp*16,+16) from OWN group's C blocks
        if (t) {
            if (tid < 64) pollge(&hflag[(g0 + tid) * 32], (unsigned)t);
            __syncthreads();
        }

        // ---------------- A: q tile (M=16b, N=16col, K=1024 over 8 waves) ----
        {
            f32x4 (*red)[64] = reinterpret_cast<f32x4(*)[64]>(smem + SMEM_SCR);
            const ushort* Arow = hb + (size_t)(qbg * 16 + frow) * ldh + wv * 128 + fk;
            const ushort* Brow = Whq + (size_t)(qc0 + frow) * H_ + wv * 128 + fk;
            f32x4 acc = (f32x4){0.f, 0.f, 0.f, 0.f};
#pragma unroll
            for (int c = 0; c < 4; ++c) {
                bf16x8 a = *reinterpret_cast<const bf16x8*>(Arow + c * 32);
                bf16x8 b = *reinterpret_cast<const bf16x8*>(Brow + c * 32);
                acc = __builtin_amdgcn_mfma_f32_16x16x32_bf16(a, b, acc, 0, 0, 0);
            }
            red[wv][lane] = acc;
            __syncthreads();
            if (wv == 0) {
                f32x4 s = red[0][lane];
#pragma unroll
                for (int w = 1; w < 8; ++w) s += red[w][lane];
                const int col = qc0 + frow;
                const float bv = bhq[col];
                const int b0 = qbg * 16 + (lane >> 4) * 4;
#pragma unroll
                for (int r = 0; r < 4; ++r)
                    atstore(&q[(size_t)(b0 + r) * H_ + col], s[r] + bv);
            }
        }
        __syncthreads();
        if (tid == 0) sigrel(&aflag[blk * 32], (unsigned)(t + 1));

        // -------- B-wait: q row ab from OWN group's A blocks ----------------
        if (tid < 64) pollge(&aflag[(g0 + tid) * 32], (unsigned)(t + 1));
        __syncthreads();

        // ---------------- B: scores -> sib sync (+enc prefetch) -> ctx ------
        {
            float qr[16];
            const float* qrow = q + (size_t)ab * H_;
            *reinterpret_cast<f32x4*>(&qr[0])  = *reinterpret_cast<const f32x4*>(qrow + lane * 8);
            *reinterpret_cast<f32x4*>(&qr[4])  = *reinterpret_cast<const f32x4*>(qrow + lane * 8 + 4);
            *reinterpret_cast<f32x4*>(&qr[8])  = *reinterpret_cast<const f32x4*>(qrow + 512 + lane * 8);
            *reinterpret_cast<f32x4*>(&qr[12]) = *reinterpret_cast<const f32x4*>(qrow + 512 + lane * 8 + 4);
#pragma unroll
            for (int i = 0; i < 4; ++i) {
                const int sl = wv * 4 + i;     // local s-row 0..31
                const char* rowp = smem + SMEM_ENCP + sl * 2048;
                u16x8 e0 = *reinterpret_cast<const u16x8*>(rowp + lane * 16);
                u16x8 e1 = *reinterpret_cast<const u16x8*>(rowp + 1024 + lane * 16);
                float p = 0.f;
#pragma unroll
                for (int j = 0; j < 8; ++j)
                    p += vr[j] * tanhf(qr[j] + bf2f(e0[j]));
#pragma unroll
                for (int j = 0; j < 8; ++j)
                    p += vr[8 + j] * tanhf(qr[8 + j] + bf2f(e1[j]));
#pragma unroll
                for (int off = 32; off; off >>= 1) p += __shfl_xor(p, off);
                if (lane == 0) atstore(&scores[ab * S_ + aq * 32 + sl], p);
            }
            __syncthreads();
            if (tid == 0) sigrel(&sflag[blk * 32], (unsigned)(t + 1));

            // prefetch B3 enc chunks (independent of alphas) under the wait
            const int e0c = aq * 512;
            const ushort* ebase = enc + (size_t)ab * S_ * ENC_ + e0c + lane * 8;
            u16x8 epre[16];
#pragma unroll
            for (int i = 0; i < 16; ++i)
                epre[i] = *reinterpret_cast<const u16x8*>(ebase + (size_t)(wv + i * 8) * ENC_);

            if (tid < 4) pollge(&sflag[(ab * 4 + tid) * 32], (unsigned)(t + 1));
            __syncthreads();

            float* part = reinterpret_cast<float*>(smem + SMEM_SCR);          // [8][512]
            float* al   = reinterpret_cast<float*>(smem + SMEM_SCR + 16384);  // [128]
            if (tid < 64) {
                float a0 = scores[ab * S_ + tid];
                float a1 = scores[ab * S_ + tid + 64];
                float m = fmaxf(a0, a1);
#pragma unroll
                for (int off = 32; off; off >>= 1) m = fmaxf(m, __shfl_xor(m, off));
                float e0v = expf(a0 - m), e1v = expf(a1 - m);
                float ssum = e0v + e1v;
#pragma unroll
                for (int off = 32; off; off >>= 1) ssum += __shfl_xor(ssum, off);
                const float inv = 1.f / ssum;
                al[tid] = e0v * inv;
                al[tid + 64] = e1v * inv;
            }
            __syncthreads();
            float acc[8];
#pragma unroll
            for (int j = 0; j < 8; ++j) acc[j] = 0.f;
#pragma unroll
            for (int i = 0; i < 16; ++i) {
                u16x8 ev = epre[i];
                const float a = al[wv + i * 8];
#pragma unroll
                for (int j = 0; j < 8; ++j)
                    acc[j] = fmaf(a, bf2f(ev[j]), acc[j]);
            }
            *reinterpret_cast<f32x4*>(part + wv * 512 + lane * 8)     = *reinterpret_cast<f32x4*>(&acc[0]);
            *reinterpret_cast<f32x4*>(part + wv * 512 + lane * 8 + 4) = *reinterpret_cast<f32x4*>(&acc[4]);
            __syncthreads();
            float scol = part[tid];
#pragma unroll
            for (int w = 1; w < 8; ++w) scol += part[w * 512 + tid];
            atstore(&ctx[(size_t)ab * ENC_ + e0c + tid], f2bf(scol));
        }
        __syncthreads();
        if (tid == 0) sigrel(&xflag[blk * 32], (unsigned)(t + 1));

        // -------- C-wait: ctx rows [cb0,+16) from OWN group's B blocks ------
        if (tid < 64) pollge(&xflag[(g0 + tid) * 32], (unsigned)(t + 1));
        __syncthreads();

        // ---------------- C: gh + gi fused + GRU (16b x 16j tile) -----------
        {
            f32x4 (*redp)[4][64] = reinterpret_cast<f32x4(*)[4][64]>(smem + SMEM_SCR);
            float (*gt)[16][16] = reinterpret_cast<float(*)[16][16]>(smem + SMEM_SCR + 32768);
            const int j0 = jt * 16;

            f32x4 a0 = (f32x4){0.f, 0.f, 0.f, 0.f};  // r: gh+gi
            f32x4 a1 = a0;                            // z: gh+gi
            f32x4 a2 = a0;                            // n input side (gi)
            f32x4 a3 = a0;                            // n hidden side (gh)

            // gh: K=1024, this wave covers [wv*128, +128)
            {
                const ushort* Ar = hb + (size_t)(cb0 + frow) * ldh + wv * 128 + fk;
                const ushort* Br = Whq + (size_t)(1024 + j0 + frow) * H_ + wv * 128 + fk;
                const ushort* Bz = Br + (size_t)1024 * H_;
                const ushort* Bn = Br + (size_t)2048 * H_;
#pragma unroll
                for (int c = 0; c < 4; ++c) {
                    bf16x8 av = *reinterpret_cast<const bf16x8*>(Ar + c * 32);
                    a0 = __builtin_amdgcn_mfma_f32_16x16x32_bf16(av, *reinterpret_cast<const bf16x8*>(Br + c * 32), a0, 0, 0, 0);
                    a1 = __builtin_amdgcn_mfma_f32_16x16x32_bf16(av, *reinterpret_cast<const bf16x8*>(Bz + c * 32), a1, 0, 0, 0);
                    a3 = __builtin_amdgcn_mfma_f32_16x16x32_bf16(av, *reinterpret_cast<const bf16x8*>(Bn + c * 32), a3, 0, 0, 0);
                }
            }
            // gi: K=2048, this wave covers [wv*256, +256)
            {
                const ushort* Ar = ctx + (size_t)(cb0 + frow) * ENC_ + wv * 256 + fk;
                const ushort* Br = Wie + (size_t)(j0 + frow) * ENC_ + wv * 256 + fk;
                const ushort* Bz = Br + (size_t)1024 * ENC_;
                const ushort* Bn = Br + (size_t)2048 * ENC_;
#pragma unroll
                for (int c = 0; c < 8; ++c) {
                    bf16x8 av = *reinterpret_cast<const bf16x8*>(Ar + c * 32);
                    a0 = __builtin_amdgcn_mfma_f32_16x16x32_bf16(av, *reinterpret_cast<const bf16x8*>(Br + c * 32), a0, 0, 0, 0);
                    a1 = __builtin_amdgcn_mfma_f32_16x16x32_bf16(av, *reinterpret_cast<const bf16x8*>(Bz + c * 32), a1, 0, 0, 0);
                    a2 = __builtin_amdgcn_mfma_f32_16x16x32_bf16(av, *reinterpret_cast<const bf16x8*>(Bn + c * 32), a2, 0, 0, 0);
                }
            }
            redp[wv][0][lane] = a0;
            redp[wv][1][lane] = a1;
            redp[wv][2][lane] = a2;
            redp[wv][3][lane] = a3;
            __syncthreads();
            if (wv < 4) {
                f32x4 s = redp[0][wv][lane];
#pragma unroll
                for (int w = 1; w < 8; ++w) s += redp[w][wv][lane];
                const int row0 = (lane >> 4) * 4;
#pragma unroll
                for (int r = 0; r < 4; ++r) gt[wv][row0 + r][frow] = s[r];
            }
            __syncthreads();
            if (tid < 256) {
                const int bl = tid >> 4, jl = tid & 15;
                const int b = cb0 + bl;
                const int j = j0 + jl;
                const size_t gr = (size_t)(b * T_ + t) * G3_;
                const float rsum = gt[0][bl][jl] + giemb[gr + j]          + bhq[1024 + j];
                const float zsum = gt[1][bl][jl] + giemb[gr + H_ + j]     + bhq[2048 + j];
                const float inn  = gt[2][bl][jl] + giemb[gr + 2 * H_ + j];
                const float hn   = gt[3][bl][jl] + bhq[3072 + j];
                const float r = sigmoidf_(rsum);
                const float z = sigmoidf_(zsum);
                const float n = tanhf(inn + r * hn);
                const float hnew = (1.f - z) * n + z * hf[(size_t)b * ldh + j];
                const size_t ho = (size_t)b * (T_ * H_) + (size_t)t * H_ + j;
                atstore(&hall_f[ho], hnew);
                atstore(&hall_b[ho], f2bf(hnew));
            }
        }
        __syncthreads();
        if (tid == 0) sigrel(&hflag[blk * 32], (unsigned)(t + 1));
    }
}

// ---------------------------------------------------------------------------
extern "C" void kernel_launch(void* const* d_in, const int* in_sizes, int n_in,
                              void* d_out, int out_size, void* d_ws, size_t ws_size,
                              hipStream_t stream) {
    const float* enc    = (const float*)d_in[0];
    const float* enc_h  = (const float*)d_in[1];
    const int*   target = (const int*)  d_in[2];
    const float* emb    = (const float*)d_in[3];
    const float* Wa     = (const float*)d_in[4];
    const float* ba     = (const float*)d_in[5];
    const float* vvec   = (const float*)d_in[6];
    const float* W_ih   = (const float*)d_in[7];
    const float* b_ih   = (const float*)d_in[8];
    const float* W_hh   = (const float*)d_in[9];
    const float* b_hh   = (const float*)d_in[10];
    const float* Wo     = (const float*)d_in[11];
    const float* bo     = (const float*)d_in[12];
    float* out = (float*)d_out;

    char* p = (char*)d_ws;
    auto alloc_u16 = [&](size_t n) { ushort* r = (ushort*)p; p += n * 2; return r; };
    auto alloc_f32 = [&](size_t n) { float* r = (float*)p; p += n * 4; return r; };

    ushort* enc_bf  = alloc_u16((size_t)B_ * S_ * ENC_);
    ushort* encp_bf = alloc_u16((size_t)B_ * S_ * H_);
    ushort* Wo_bf   = alloc_u16((size_t)V_ * H_);
    ushort* Wae_bf  = alloc_u16((size_t)H_ * ENC_);
    ushort* Whq_bf  = alloc_u16((size_t)QGH_ * H_);
    ushort* Wie_bf  = alloc_u16((size_t)G3_ * ENC_);
    ushort* Wiee_bf = alloc_u16((size_t)G3_ * E_);
    ushort* ench_bf = alloc_u16((size_t)B_ * H_);
    ushort* Xemb_bf = alloc_u16((size_t)B_ * T_ * E_);
    ushort* hall_bf = alloc_u16((size_t)B_ * T_ * H_);
    ushort* ctx_all = alloc_u16((size_t)T_ * B_ * ENC_);   // step-unique
    float* hall_f   = alloc_f32((size_t)B_ * T_ * H_);
    float* giemb    = alloc_f32((size_t)B_ * T_ * G3_);
    float* q_all    = alloc_f32((size_t)T_ * B_ * H_);     // step-unique
    float* scr_all  = alloc_f32((size_t)T_ * B_ * S_);     // step-unique
    float* bhq      = alloc_f32((size_t)QGH_);
    unsigned* flags = (unsigned*)alloc_f32(33024);   // 4 x 8192 + slack
    unsigned* aflag = flags;
    unsigned* sflag = flags + 8192;
    unsigned* xflag = flags + 16384;
    unsigned* hflag = flags + 24576;

    // ---- ONE merged pack/convert/init kernel ----
    pack_all<<<dim3(2048, 9), 256, 0, stream>>>(
        enc, Wo, Wa, W_hh, W_ih, enc_h, ba, b_hh, b_ih, target, emb,
        enc_bf, Wo_bf, Wae_bf, Whq_bf, Wie_bf, Wiee_bf, ench_bf, Xemb_bf,
        bhq, flags);

    // ---- big parallel GEMMs ----
    gemm128_bf16<<<dim3(H_/128, (B_*S_)/128), 256, 0, stream>>>(
        enc_bf, ENC_, Wae_bf, ENC_, nullptr, nullptr, encp_bf, H_, ENC_);
    gemm128_bf16<<<dim3(G3_/128, (B_*T_)/128), 256, 0, stream>>>(
        Xemb_bf, E_, Wiee_bf, E_, b_ih, giemb, nullptr, G3_, E_);

    // ---- persistent recurrence (closed groups, 100 KB dynamic LDS) ----
    decoder_persist<<<NB_, 512, SMEM_TOTAL, stream>>>(
        encp_bf, enc_bf, ench_bf, enc_h, Whq_bf, Wie_bf, bhq, vvec, giemb,
        q_all, scr_all, ctx_all, hall_f, hall_bf, aflag, sflag, xflag, hflag);

    // ---- output projection ----
    gemm128_bf16<<<dim3(V_/128, (B_*T_)/128), 256, 0, stream>>>(
        hall_bf, H_, Wo_bf, H_, bo, out, nullptr, V_, H_);
}

// Round 17
// 2789.422 us; speedup vs baseline: 1.1377x; 1.1377x over previous
//
#include <hip/hip_runtime.h>
#include <hip/hip_bf16.h>

#define B_   64
#define S_   128
#define T_   64
#define H_   1024
#define E_   512
#define V_   16000
#define ENC_ 2048
#define XDIM_ (E_ + ENC_)   // 2560
#define G3_  (3 * H_)       // 3072
#define QGH_ (4 * H_)       // 4096 (bhq layout: ba | bhh_r | bhh_z | bhh_n)
#define NB_  256            // persistent grid size

// dynamic LDS layout (bytes)
#define SMEM_ENCP   0        // 32 rows x 2048 B = 65536
#define SMEM_SCR    65536    // phase scratch (max: C redp 32768 + gt 4096)
#define SMEM_TOTAL  102400

typedef __attribute__((ext_vector_type(8))) short bf16x8;
typedef __attribute__((ext_vector_type(8))) unsigned short u16x8;
typedef __attribute__((ext_vector_type(4))) float f32x4;

__device__ __forceinline__ ushort f2bf(float x) {
    __hip_bfloat16 h = __float2bfloat16(x);
    return *reinterpret_cast<ushort*>(&h);
}
__device__ __forceinline__ float bf2f(ushort u) {
    return __uint_as_float((unsigned)u << 16);
}
__device__ __forceinline__ float sigmoidf_(float x) {
    return 1.f / (1.f + expf(-x));
}

// Relaxed agent-scope atomic store: lands at the LLC coherence point, no L2
// dirty allocation. Ordering to the flag store is via __syncthreads(): each
// wave's vmcnt is drained at barrier arrival, so by the time tid0 stores the
// flag, all data stores have retired. (R12-proven.)
template <typename T>
__device__ __forceinline__ void atstore(T* p, T v) {
    __hip_atomic_store(p, v, __ATOMIC_RELAXED, __HIP_MEMORY_SCOPE_AGENT);
}

// async global->LDS, 16B per lane
__device__ __forceinline__ void gload_lds16(const ushort* g, ushort* l) {
    __builtin_amdgcn_global_load_lds(
        (const __attribute__((address_space(1))) unsigned int*)g,
        (__attribute__((address_space(3))) unsigned int*)l, 16, 0, 0);
}

__device__ __forceinline__ void pollge(const unsigned* f, unsigned v) {
    while (__hip_atomic_load(f, __ATOMIC_RELAXED, __HIP_MEMORY_SCOPE_AGENT) < v)
        __builtin_amdgcn_s_sleep(1);
}
__device__ __forceinline__ void sigrel(unsigned* f, unsigned v) {
    __hip_atomic_store(f, v, __ATOMIC_RELAXED, __HIP_MEMORY_SCOPE_AGENT);
}

// ---------------------------------------------------------------------------
// m97-structure GEMM: C[M,N] = A[M,K] @ W[N,K]^T + bias[N]
// ---------------------------------------------------------------------------
__global__ __launch_bounds__(256) void gemm128_bf16(
    const ushort* __restrict__ A, int lda,
    const ushort* __restrict__ W, int ldw,
    const float* __restrict__ bias,
    float* __restrict__ Cf, ushort* __restrict__ Cb, int ldc,
    int K)
{
    const int bn0 = blockIdx.x * 128;
    const int bm0 = blockIdx.y * 128;
    const int tid = threadIdx.x;
    const int wv  = tid >> 6;
    const int lane = tid & 63;

    __shared__ ushort As[128 * 32];
    __shared__ ushort Bs[128 * 32];

    const int srow = tid >> 2;
    const int scol = (tid & 3) * 8;

    const ushort* gA0 = A + (size_t)(bm0 + srow) * lda + scol;
    const ushort* gA1 = gA0 + (size_t)64 * lda;
    const ushort* gB0 = W + (size_t)(bn0 + srow) * ldw + scol;
    const ushort* gB1 = gB0 + (size_t)64 * ldw;

    ushort* lA0 = &As[tid * 8];
    ushort* lA1 = &As[2048 + tid * 8];
    ushort* lB0 = &Bs[tid * 8];
    ushort* lB1 = &Bs[2048 + tid * 8];

    const int wr0 = (wv >> 1) * 64;
    const int wc0 = (wv & 1) * 64;
    const int frow = lane & 15;
    const int fk   = (lane >> 4) * 8;

    f32x4 acc[4][4];
#pragma unroll
    for (int i = 0; i < 4; ++i)
#pragma unroll
        for (int j = 0; j < 4; ++j) acc[i][j] = (f32x4){0.f, 0.f, 0.f, 0.f};

    for (int k0 = 0; k0 < K; k0 += 32) {
        gload_lds16(gA0 + k0, lA0);
        gload_lds16(gA1 + k0, lA1);
        gload_lds16(gB0 + k0, lB0);
        gload_lds16(gB1 + k0, lB1);
        __syncthreads();

        bf16x8 af[4], bf[4];
#pragma unroll
        for (int rb = 0; rb < 4; ++rb)
            af[rb] = *reinterpret_cast<const bf16x8*>(&As[(wr0 + rb * 16 + frow) * 32 + fk]);
#pragma unroll
        for (int cb = 0; cb < 4; ++cb)
            bf[cb] = *reinterpret_cast<const bf16x8*>(&Bs[(wc0 + cb * 16 + frow) * 32 + fk]);
#pragma unroll
        for (int rb = 0; rb < 4; ++rb)
#pragma unroll
            for (int cb = 0; cb < 4; ++cb)
                acc[rb][cb] = __builtin_amdgcn_mfma_f32_16x16x32_bf16(af[rb], bf[cb], acc[rb][cb], 0, 0, 0);
        __syncthreads();
    }

    const int quad = lane >> 4;
#pragma unroll
    for (int cb = 0; cb < 4; ++cb) {
        const int col = bn0 + wc0 + cb * 16 + frow;
        const float bv = bias ? bias[col] : 0.f;
#pragma unroll
        for (int rb = 0; rb < 4; ++rb) {
            const int row0 = bm0 + wr0 + rb * 16 + quad * 4;
            f32x4 a = acc[rb][cb];
#pragma unroll
            for (int r = 0; r < 4; ++r) {
                const float val = a[r] + bv;
                if (Cb) Cb[(size_t)(row0 + r) * ldc + col] = f2bf(val);
                else    Cf[(size_t)(row0 + r) * ldc + col] = val;
            }
        }
    }
}

// ---------------------------------------------------------------------------
// ONE merged pack kernel: all f32->bf16 conversions, bias pack, flag zeroing,
// and embedding gather. grid = (2048, 9); each y-slice grid-strides its
// segment.
// ---------------------------------------------------------------------------
__global__ __launch_bounds__(256) void pack_all(
    const float* __restrict__ enc,     // (B,S,ENC)
    const float* __restrict__ Wo,      // (V,H)
    const float* __restrict__ Wa,      // (H, 3072)
    const float* __restrict__ W_hh,    // (3H, H)
    const float* __restrict__ W_ih,    // (3H, 2560)
    const float* __restrict__ enc_h,   // (B,H)
    const float* __restrict__ ba,
    const float* __restrict__ b_hh,
    const float* __restrict__ b_ih,    // unused here (giemb GEMM adds it)
    const int*   __restrict__ target,
    const float* __restrict__ emb,
    ushort* __restrict__ enc_bf,
    ushort* __restrict__ Wo_bf,
    ushort* __restrict__ Wae_bf,
    ushort* __restrict__ Whq_bf,
    ushort* __restrict__ Wie_bf,
    ushort* __restrict__ Wiee_bf,
    ushort* __restrict__ ench_bf,
    ushort* __restrict__ Xemb_bf,
    float*  __restrict__ bhq,
    unsigned* __restrict__ flags)
{
    const size_t stride = (size_t)gridDim.x * 256;
    const size_t i0 = (size_t)blockIdx.x * 256 + threadIdx.x;

    switch (blockIdx.y) {
    case 0:  // enc (dense)
        for (size_t i = i0; i < (size_t)B_ * S_ * ENC_; i += stride)
            enc_bf[i] = f2bf(enc[i]);
        break;
    case 1:  // Wo (dense)
        for (size_t i = i0; i < (size_t)V_ * H_; i += stride)
            Wo_bf[i] = f2bf(Wo[i]);
        break;
    case 2:  // Wa cols [H, H+ENC) -> Wae
        for (size_t i = i0; i < (size_t)H_ * ENC_; i += stride) {
            const size_t r = i >> 11, c = i & 2047;
            Wae_bf[i] = f2bf(Wa[r * 3072 + 1024 + c]);
        }
        break;
    case 3:  // Wa cols [0,H) -> Whq[0:H]
        for (size_t i = i0; i < (size_t)H_ * H_; i += stride) {
            const size_t r = i >> 10, c = i & 1023;
            Whq_bf[i] = f2bf(Wa[r * 3072 + c]);
        }
        break;
    case 4:  // W_hh (dense) -> Whq[H:4H]
        for (size_t i = i0; i < (size_t)G3_ * H_; i += stride)
            Whq_bf[(size_t)H_ * H_ + i] = f2bf(W_hh[i]);
        break;
    case 5:  // W_ih cols [E, E+ENC) -> Wie
        for (size_t i = i0; i < (size_t)G3_ * ENC_; i += stride) {
            const size_t r = i >> 11, c = i & 2047;
            Wie_bf[i] = f2bf(W_ih[r * 2560 + 512 + c]);
        }
        break;
    case 6:  // W_ih cols [0,E) -> Wiee
        for (size_t i = i0; i < (size_t)G3_ * E_; i += stride) {
            const size_t r = i >> 9, c = i & 511;
            Wiee_bf[i] = f2bf(W_ih[r * 2560 + c]);
        }
        break;
    case 7:  // ench (dense) + bhq + flag zero
        for (size_t i = i0; i < (size_t)B_ * H_ + 4096 + 32768; i += stride) {
            if (i < (size_t)B_ * H_) {
                ench_bf[i] = f2bf(enc_h[i]);
            } else if (i < (size_t)B_ * H_ + 4096) {
                const int j = (int)(i - (size_t)B_ * H_);
                bhq[j] = (j < H_) ? ba[j] : b_hh[j - H_];
            } else {
                flags[i - (size_t)B_ * H_ - 4096] = 0u;
            }
        }
        break;
    case 8:  // embedding gather: row b*T+t <- emb[token(b,t)]
        for (size_t i = i0; i < (size_t)B_ * T_ * E_; i += stride) {
            const int row = (int)(i >> 9);
            const int c = (int)(i & 511);
            const int b = row >> 6, t = row & 63;
            const int tok = (t == 0) ? 1 : target[b * T_ + t - 1];
            Xemb_bf[i] = f2bf(emb[(size_t)tok * E_ + c]);
        }
        break;
    }
}

// ---------------------------------------------------------------------------
// Persistent decoder — single-hop dependency polling (R13/R15, verified best).
// Per step:
//   [A-wait: 64 hflags {4i+qbg}] A: q tile -> aflag
//   [B-wait: 64 aflags group]    B: scores -> sib sflag -> softmax+ctx -> xflag
//   [C-wait: 64 xflags cb0*4..]  C: gh+gi fused + GRU -> hflag
// C's h(t-1) read is transitively covered (chain C->B->A->C(t-1), rows match).
// All data step-unique; publication relaxed-atomic + syncthreads (R12 model).
// ---------------------------------------------------------------------------
__global__ __launch_bounds__(512) void decoder_persist(
    const ushort* __restrict__ encp,   // (B,S,H) bf16
    const ushort* __restrict__ enc,    // (B,S,ENC) bf16
    const ushort* __restrict__ ench,   // (B,H) bf16 h0
    const float*  __restrict__ ench_f, // (B,H) fp32 h0
    const ushort* __restrict__ Whq,    // (4096,1024) bf16: [Wa_q | Whh_r | Whh_z | Whh_n]
    const ushort* __restrict__ Wie,    // (3072,2048) bf16
    const float*  __restrict__ bhq,    // (4096): [ba | bhh_r | bhh_z | bhh_n]
    const float*  __restrict__ vvec,   // (1024)
    const float*  __restrict__ giemb,  // (B*T,3H) fp32 (incl b_ih)
    float* __restrict__ q_all,         // (T,B,H) step-unique
    float* __restrict__ scores_all,    // (T,B,S) step-unique
    ushort* __restrict__ ctx_all,      // (T,B,ENC) bf16 step-unique
    float* __restrict__ hall_f,        // (B,T,H)
    ushort* __restrict__ hall_b,       // (B,T,H)
    unsigned* __restrict__ aflag,
    unsigned* __restrict__ sflag,
    unsigned* __restrict__ xflag,
    unsigned* __restrict__ hflag)
{
    extern __shared__ __align__(16) char smem[];
    const int blk = blockIdx.x;
    const int tid = threadIdx.x;
    const int wv = tid >> 6;
    const int lane = tid & 63;
    const int frow = lane & 15;
    const int fk = (lane >> 4) * 8;

    const int ab = blk >> 2;           // B-task: b
    const int aq = blk & 3;            // B-task: quarter
    const int qbg = blk >> 6;          // A-task: b-group (0..3)
    const int qc0 = (blk & 63) * 16;   // A-task: col base (0..1008)
    const int jt = blk >> 2;           // C-task: j-slice
    const int cb0 = (blk & 3) * 16;    // C-task: b base

    // ---- preload encp slice (b=ab, rows aq*32..+32) into LDS ----
    {
        const char* src = (const char*)(encp + ((size_t)ab * S_ + aq * 32) * H_);
#pragma unroll
        for (int r = 0; r < 8; ++r) {
            const int ci = r * 8 + wv;
            gload_lds16((const ushort*)(src + ci * 1024 + lane * 16),
                        (ushort*)(smem + SMEM_ENCP + ci * 1024 + lane * 16));
        }
    }
    float vr[16];
    *reinterpret_cast<f32x4*>(&vr[0])  = *reinterpret_cast<const f32x4*>(vvec + lane * 8);
    *reinterpret_cast<f32x4*>(&vr[4])  = *reinterpret_cast<const f32x4*>(vvec + lane * 8 + 4);
    *reinterpret_cast<f32x4*>(&vr[8])  = *reinterpret_cast<const f32x4*>(vvec + 512 + lane * 8);
    *reinterpret_cast<f32x4*>(&vr[12]) = *reinterpret_cast<const f32x4*>(vvec + 512 + lane * 8 + 4);
    __syncthreads();

    for (int t = 0; t < T_; ++t) {
        const ushort* hb = t ? (hall_b + (size_t)(t - 1) * H_) : ench;
        const float*  hf = t ? (hall_f + (size_t)(t - 1) * H_) : ench_f;
        const int ldh = t ? (T_ * H_) : H_;
        float* q = q_all + (size_t)t * B_ * H_;
        float* scores = scores_all + (size_t)t * B_ * S_;
        ushort* ctx = ctx_all + (size_t)t * B_ * ENC_;

        // -------- A-wait: h(t-1) rows [qbg*16,+16) from C blocks {4i+qbg} ---
        if (t) {
            if (tid < 64) pollge(&hflag[(tid * 4 + qbg) * 32], (unsigned)t);
            __syncthreads();
        }

        // ---------------- A: q tile (M=16b, N=16col, K=1024 over 8 waves) ----
        {
            f32x4 (*red)[64] = reinterpret_cast<f32x4(*)[64]>(smem + SMEM_SCR);
            const ushort* Arow = hb + (size_t)(qbg * 16 + frow) * ldh + wv * 128 + fk;
            const ushort* Brow = Whq + (size_t)(qc0 + frow) * H_ + wv * 128 + fk;
            f32x4 acc = (f32x4){0.f, 0.f, 0.f, 0.f};
#pragma unroll
            for (int c = 0; c < 4; ++c) {
                bf16x8 a = *reinterpret_cast<const bf16x8*>(Arow + c * 32);
                bf16x8 b = *reinterpret_cast<const bf16x8*>(Brow + c * 32);
                acc = __builtin_amdgcn_mfma_f32_16x16x32_bf16(a, b, acc, 0, 0, 0);
            }
            red[wv][lane] = acc;
            __syncthreads();
            if (wv == 0) {
                f32x4 s = red[0][lane];
#pragma unroll
                for (int w = 1; w < 8; ++w) s += red[w][lane];
                const int col = qc0 + frow;
                const float bv = bhq[col];
                const int b0 = qbg * 16 + (lane >> 4) * 4;
#pragma unroll
                for (int r = 0; r < 4; ++r)
                    atstore(&q[(size_t)(b0 + r) * H_ + col], s[r] + bv);
            }
        }
        __syncthreads();
        if (tid == 0) sigrel(&aflag[blk * 32], (unsigned)(t + 1));

        // -------- B-wait: q row ab from A blocks [(ab>>4)*64, +64) ----------
        if (tid < 64) pollge(&aflag[((ab >> 4) * 64 + tid) * 32], (unsigned)(t + 1));
        __syncthreads();

        // ---------------- B: scores -> sib sync (+enc prefetch) -> ctx ------
        {
            float qr[16];
            const float* qrow = q + (size_t)ab * H_;
            *reinterpret_cast<f32x4*>(&qr[0])  = *reinterpret_cast<const f32x4*>(qrow + lane * 8);
            *reinterpret_cast<f32x4*>(&qr[4])  = *reinterpret_cast<const f32x4*>(qrow + lane * 8 + 4);
            *reinterpret_cast<f32x4*>(&qr[8])  = *reinterpret_cast<const f32x4*>(qrow + 512 + lane * 8);
            *reinterpret_cast<f32x4*>(&qr[12]) = *reinterpret_cast<const f32x4*>(qrow + 512 + lane * 8 + 4);
#pragma unroll
            for (int i = 0; i < 4; ++i) {
                const int sl = wv * 4 + i;     // local s-row 0..31
                const char* rowp = smem + SMEM_ENCP + sl * 2048;
                u16x8 e0 = *reinterpret_cast<const u16x8*>(rowp + lane * 16);
                u16x8 e1 = *reinterpret_cast<const u16x8*>(rowp + 1024 + lane * 16);
                float p = 0.f;
#pragma unroll
                for (int j = 0; j < 8; ++j)
                    p += vr[j] * tanhf(qr[j] + bf2f(e0[j]));
#pragma unroll
                for (int j = 0; j < 8; ++j)
                    p += vr[8 + j] * tanhf(qr[8 + j] + bf2f(e1[j]));
#pragma unroll
                for (int off = 32; off; off >>= 1) p += __shfl_xor(p, off);
                if (lane == 0) atstore(&scores[ab * S_ + aq * 32 + sl], p);
            }
            __syncthreads();
            if (tid == 0) sigrel(&sflag[blk * 32], (unsigned)(t + 1));

            // prefetch B3 enc chunks (independent of alphas) under the wait
            const int e0c = aq * 512;
            const ushort* ebase = enc + (size_t)ab * S_ * ENC_ + e0c + lane * 8;
            u16x8 epre[16];
#pragma unroll
            for (int i = 0; i < 16; ++i)
                epre[i] = *reinterpret_cast<const u16x8*>(ebase + (size_t)(wv + i * 8) * ENC_);

            if (tid < 4) pollge(&sflag[(ab * 4 + tid) * 32], (unsigned)(t + 1));
            __syncthreads();

            float* part = reinterpret_cast<float*>(smem + SMEM_SCR);          // [8][512]
            float* al   = reinterpret_cast<float*>(smem + SMEM_SCR + 16384);  // [128]
            if (tid < 64) {
                float a0 = scores[ab * S_ + tid];
                float a1 = scores[ab * S_ + tid + 64];
                float m = fmaxf(a0, a1);
#pragma unroll
                for (int off = 32; off; off >>= 1) m = fmaxf(m, __shfl_xor(m, off));
                float e0v = expf(a0 - m), e1v = expf(a1 - m);
                float ssum = e0v + e1v;
#pragma unroll
                for (int off = 32; off; off >>= 1) ssum += __shfl_xor(ssum, off);
                const float inv = 1.f / ssum;
                al[tid] = e0v * inv;
                al[tid + 64] = e1v * inv;
            }
            __syncthreads();
            float acc[8];
#pragma unroll
            for (int j = 0; j < 8; ++j) acc[j] = 0.f;
#pragma unroll
            for (int i = 0; i < 16; ++i) {
                u16x8 ev = epre[i];
                const float a = al[wv + i * 8];
#pragma unroll
                for (int j = 0; j < 8; ++j)
                    acc[j] = fmaf(a, bf2f(ev[j]), acc[j]);
            }
            *reinterpret_cast<f32x4*>(part + wv * 512 + lane * 8)     = *reinterpret_cast<f32x4*>(&acc[0]);
            *reinterpret_cast<f32x4*>(part + wv * 512 + lane * 8 + 4) = *reinterpret_cast<f32x4*>(&acc[4]);
            __syncthreads();
            float scol = part[tid];
#pragma unroll
            for (int w = 1; w < 8; ++w) scol += part[w * 512 + tid];
            atstore(&ctx[(size_t)ab * ENC_ + e0c + tid], f2bf(scol));
        }
        __syncthreads();
        if (tid == 0) sigrel(&xflag[blk * 32], (unsigned)(t + 1));

        // -------- C-wait: ctx rows [cb0,+16) from B blocks [cb0*4, +64) -----
        if (tid < 64) pollge(&xflag[(cb0 * 4 + tid) * 32], (unsigned)(t + 1));
        __syncthreads();

        // ---------------- C: gh + gi fused + GRU (16b x 16j tile) -----------
        {
            f32x4 (*redp)[4][64] = reinterpret_cast<f32x4(*)[4][64]>(smem + SMEM_SCR);
            float (*gt)[16][16] = reinterpret_cast<float(*)[16][16]>(smem + SMEM_SCR + 32768);
            const int j0 = jt * 16;

            f32x4 a0 = (f32x4){0.f, 0.f, 0.f, 0.f};  // r: gh+gi
            f32x4 a1 = a0;                            // z: gh+gi
            f32x4 a2 = a0;                            // n input side (gi)
            f32x4 a3 = a0;                            // n hidden side (gh)

            // gh: K=1024, this wave covers [wv*128, +128)
            {
                const ushort* Ar = hb + (size_t)(cb0 + frow) * ldh + wv * 128 + fk;
                const ushort* Br = Whq + (size_t)(1024 + j0 + frow) * H_ + wv * 128 + fk;
                const ushort* Bz = Br + (size_t)1024 * H_;
                const ushort* Bn = Br + (size_t)2048 * H_;
#pragma unroll
                for (int c = 0; c < 4; ++c) {
                    bf16x8 av = *reinterpret_cast<const bf16x8*>(Ar + c * 32);
                    a0 = __builtin_amdgcn_mfma_f32_16x16x32_bf16(av, *reinterpret_cast<const bf16x8*>(Br + c * 32), a0, 0, 0, 0);
                    a1 = __builtin_amdgcn_mfma_f32_16x16x32_bf16(av, *reinterpret_cast<const bf16x8*>(Bz + c * 32), a1, 0, 0, 0);
                    a3 = __builtin_amdgcn_mfma_f32_16x16x32_bf16(av, *reinterpret_cast<const bf16x8*>(Bn + c * 32), a3, 0, 0, 0);
                }
            }
            // gi: K=2048, this wave covers [wv*256, +256)
            {
                const ushort* Ar = ctx + (size_t)(cb0 + frow) * ENC_ + wv * 256 + fk;
                const ushort* Br = Wie + (size_t)(j0 + frow) * ENC_ + wv * 256 + fk;
                const ushort* Bz = Br + (size_t)1024 * ENC_;
                const ushort* Bn = Br + (size_t)2048 * ENC_;
#pragma unroll
                for (int c = 0; c < 8; ++c) {
                    bf16x8 av = *reinterpret_cast<const bf16x8*>(Ar + c * 32);
                    a0 = __builtin_amdgcn_mfma_f32_16x16x32_bf16(av, *reinterpret_cast<const bf16x8*>(Br + c * 32), a0, 0, 0, 0);
                    a1 = __builtin_amdgcn_mfma_f32_16x16x32_bf16(av, *reinterpret_cast<const bf16x8*>(Bz + c * 32), a1, 0, 0, 0);
                    a2 = __builtin_amdgcn_mfma_f32_16x16x32_bf16(av, *reinterpret_cast<const bf16x8*>(Bn + c * 32), a2, 0, 0, 0);
                }
            }
            redp[wv][0][lane] = a0;
            redp[wv][1][lane] = a1;
            redp[wv][2][lane] = a2;
            redp[wv][3][lane] = a3;
            __syncthreads();
            if (wv < 4) {
                f32x4 s = redp[0][wv][lane];
#pragma unroll
                for (int w = 1; w < 8; ++w) s += redp[w][wv][lane];
                const int row0 = (lane >> 4) * 4;
#pragma unroll
                for (int r = 0; r < 4; ++r) gt[wv][row0 + r][frow] = s[r];
            }
            __syncthreads();
            if (tid < 256) {
                const int bl = tid >> 4, jl = tid & 15;
                const int b = cb0 + bl;
                const int j = j0 + jl;
                const size_t gr = (size_t)(b * T_ + t) * G3_;
                const float rsum = gt[0][bl][jl] + giemb[gr + j]          + bhq[1024 + j];
                const float zsum = gt[1][bl][jl] + giemb[gr + H_ + j]     + bhq[2048 + j];
                const float inn  = gt[2][bl][jl] + giemb[gr + 2 * H_ + j];
                const float hn   = gt[3][bl][jl] + bhq[3072 + j];
                const float r = sigmoidf_(rsum);
                const float z = sigmoidf_(zsum);
                const float n = tanhf(inn + r * hn);
                const float hnew = (1.f - z) * n + z * hf[(size_t)b * ldh + j];
                const size_t ho = (size_t)b * (T_ * H_) + (size_t)t * H_ + j;
                atstore(&hall_f[ho], hnew);
                atstore(&hall_b[ho], f2bf(hnew));
            }
        }
        __syncthreads();
        if (tid == 0) sigrel(&hflag[blk * 32], (unsigned)(t + 1));
    }
}

// ---------------------------------------------------------------------------
extern "C" void kernel_launch(void* const* d_in, const int* in_sizes, int n_in,
                              void* d_out, int out_size, void* d_ws, size_t ws_size,
                              hipStream_t stream) {
    const float* enc    = (const float*)d_in[0];
    const float* enc_h  = (const float*)d_in[1];
    const int*   target = (const int*)  d_in[2];
    const float* emb    = (const float*)d_in[3];
    const float* Wa     = (const float*)d_in[4];
    const float* ba     = (const float*)d_in[5];
    const float* vvec   = (const float*)d_in[6];
    const float* W_ih   = (const float*)d_in[7];
    const float* b_ih   = (const float*)d_in[8];
    const float* W_hh   = (const float*)d_in[9];
    const float* b_hh   = (const float*)d_in[10];
    const float* Wo     = (const float*)d_in[11];
    const float* bo     = (const float*)d_in[12];
    float* out = (float*)d_out;

    char* p = (char*)d_ws;
    auto alloc_u16 = [&](size_t n) { ushort* r = (ushort*)p; p += n * 2; return r; };
    auto alloc_f32 = [&](size_t n) { float* r = (float*)p; p += n * 4; return r; };

    ushort* enc_bf  = alloc_u16((size_t)B_ * S_ * ENC_);
    ushort* encp_bf = alloc_u16((size_t)B_ * S_ * H_);
    ushort* Wo_bf   = alloc_u16((size_t)V_ * H_);
    ushort* Wae_bf  = alloc_u16((size_t)H_ * ENC_);
    ushort* Whq_bf  = alloc_u16((size_t)QGH_ * H_);
    ushort* Wie_bf  = alloc_u16((size_t)G3_ * ENC_);
    ushort* Wiee_bf = alloc_u16((size_t)G3_ * E_);
    ushort* ench_bf = alloc_u16((size_t)B_ * H_);
    ushort* Xemb_bf = alloc_u16((size_t)B_ * T_ * E_);
    ushort* hall_bf = alloc_u16((size_t)B_ * T_ * H_);
    ushort* ctx_all = alloc_u16((size_t)T_ * B_ * ENC_);   // step-unique
    float* hall_f   = alloc_f32((size_t)B_ * T_ * H_);
    float* giemb    = alloc_f32((size_t)B_ * T_ * G3_);
    float* q_all    = alloc_f32((size_t)T_ * B_ * H_);     // step-unique
    float* scr_all  = alloc_f32((size_t)T_ * B_ * S_);     // step-unique
    float* bhq      = alloc_f32((size_t)QGH_);
    unsigned* flags = (unsigned*)alloc_f32(33024);   // 4 x 8192 + slack
    unsigned* aflag = flags;
    unsigned* sflag = flags + 8192;
    unsigned* xflag = flags + 16384;
    unsigned* hflag = flags + 24576;

    // ---- ONE merged pack/convert/init kernel ----
    pack_all<<<dim3(2048, 9), 256, 0, stream>>>(
        enc, Wo, Wa, W_hh, W_ih, enc_h, ba, b_hh, b_ih, target, emb,
        enc_bf, Wo_bf, Wae_bf, Whq_bf, Wie_bf, Wiee_bf, ench_bf, Xemb_bf,
        bhq, flags);

    // ---- big parallel GEMMs ----
    gemm128_bf16<<<dim3(H_/128, (B_*S_)/128), 256, 0, stream>>>(
        enc_bf, ENC_, Wae_bf, ENC_, nullptr, nullptr, encp_bf, H_, ENC_);
    gemm128_bf16<<<dim3(G3_/128, (B_*T_)/128), 256, 0, stream>>>(
        Xemb_bf, E_, Wiee_bf, E_, b_ih, giemb, nullptr, G3_, E_);

    // ---- persistent recurrence (100 KB dynamic LDS) ----
    decoder_persist<<<NB_, 512, SMEM_TOTAL, stream>>>(
        encp_bf, enc_bf, ench_bf, enc_h, Whq_bf, Wie_bf, bhq, vvec, giemb,
        q_all, scr_all, ctx_all, hall_f, hall_bf, aflag, sflag, xflag, hflag);

    // ---- output projection ----
    gemm128_bf16<<<dim3(V_/128, (B_*T_)/128), 256, 0, stream>>>(
        hall_bf, H_, Wo_bf, H_, bo, out, nullptr, V_, H_);
}